// Round 1
// baseline (336.645 us; speedup 1.0000x reference)
//
#include <hip/hip_runtime.h>
#include <math.h>

static constexpr int D   = 128;   // embedding dim (per reference)
static constexpr int NL  = 64;    // number of label buckets (labels in [0,64))
static constexpr int RT  = 32;    // rows per block in pass2
static constexpr int CT  = 64;    // col tile in pass2
static constexpr int PAD = 4;     // LDS row padding (floats), keeps 16B alignment

#define EPS_F 1e-7f

__device__ __forceinline__ float wave_reduce_sum(float v) {
  #pragma unroll
  for (int o = 32; o; o >>= 1) v += __shfl_xor(v, o, 64);
  return v;
}
__device__ __forceinline__ float wave_reduce_max(float v) {
  #pragma unroll
  for (int o = 32; o; o >>= 1) v = fmaxf(v, __shfl_xor(v, o, 64));
  return v;
}

// acosh for arg >= 1, fast-path (tolerance is ~2%, this is ~1e-6 rel)
__device__ __forceinline__ float fast_acosh(float arg) {
  float x = fmaxf(arg, 1.0f);
  float s = __builtin_amdgcn_sqrtf(fmaf(x, x, -1.0f));
  return __logf(x + s);
}

__device__ __forceinline__ float pair_dist(float dot, float si, float sj,
                                           float oi, float oj) {
  float diff = fmaxf(si + sj - 2.0f * dot, 0.0f);
  float den  = fmaxf(oi * oj, EPS_F);
  float arg  = fmaf(2.0f * diff, __builtin_amdgcn_rcpf(den), 1.0f);
  return fast_acosh(arg);
}

// K0: zero scalar accumulators + label histogram
__global__ void k0_zero(float* acc, int* LC) {
  int t = threadIdx.x;
  if (t < 8)  acc[t] = 0.0f;
  if (t < NL) LC[t]  = 0;
}

// K1: per-row sq, 1-sq, margin; label histogram. One wave per row.
__global__ void k1_rowstats(const float* __restrict__ emb, const int* __restrict__ lab,
                            float* sq, float* om, float* mg, int* LC, int B) {
  int wid  = threadIdx.x >> 6;
  int lane = threadIdx.x & 63;
  int i = blockIdx.x * 4 + wid;
  if (i >= B) return;
  const float2* e2 = reinterpret_cast<const float2*>(emb + (size_t)i * D);
  float2 v = e2[lane];
  float s = wave_reduce_sum(v.x * v.x + v.y * v.y);
  if (lane == 0) {
    sq[i] = s;
    om[i] = 1.0f - s;
    mg[i] = fmaxf(1.0f * (1.0f + 2.0f * sqrtf(s)), 0.1f);  // MARGIN=1, BF=2, THR=0.1
    atomicAdd(&LC[lab[i]], 1);
  }
}

// K2: label prefix sums + analytic pos_cnt / total_triplets (exact, < 2^24)
__global__ void k2_prefix(float* acc, const int* LC, int* LOFF, int* LCUR, int B) {
  if (threadIdx.x == 0 && blockIdx.x == 0) {
    int off = 0;
    double pc = 0.0, trip = 0.0;
    for (int l = 0; l < NL; ++l) {
      int c = LC[l];
      LOFF[l] = off; LCUR[l] = off; off += c;
      pc += (double)c * (double)(c - 1);
      if (c >= 2 && c < B) trip += (double)c * (double)(B - c);
    }
    acc[3] = (float)pc;    // pos_count
    acc[4] = (float)trip;  // total_triplets
  }
}

// K3: scatter indices sorted by label
__global__ void k3_scatter(const int* __restrict__ lab, int* LCUR, int* SIDX, int B) {
  int i = blockIdx.x * blockDim.x + threadIdx.x;
  if (i < B) {
    int p = atomicAdd(&LCUR[lab[i]], 1);
    SIDX[p] = i;
  }
}

// K4: per-row positive pass (same-label pairs only, ~64/row).
// Computes hpm[i] = valid ? hardest_pos + margin : -1e30, and pos distance sum.
__global__ __launch_bounds__(128) void k4_pos(
    const float* __restrict__ emb, const int* __restrict__ lab,
    const int* __restrict__ LC, const int* __restrict__ LOFF,
    const int* __restrict__ SIDX, const float* __restrict__ sq,
    const float* __restrict__ om, const float* __restrict__ mg,
    float* hpm, float* acc, int B) {
  __shared__ float xi[D];
  __shared__ float red[8];
  int i = blockIdx.x;
  int t = threadIdx.x;
  if (t < D) xi[t] = emb[(size_t)i * D + t];
  __syncthreads();
  int li = lab[i];
  int c = LC[li];
  int base = LOFF[li];
  float si = sq[i], oi = om[i];
  float mymax = -1e30f, mysum = 0.0f;
  const float4* xi4 = reinterpret_cast<const float4*>(xi);
  for (int p = t; p < c; p += 128) {
    int j = SIDX[base + p];
    if (j == i) continue;
    const float4* xj4 = reinterpret_cast<const float4*>(emb + (size_t)j * D);
    float dot = 0.0f;
    #pragma unroll
    for (int q = 0; q < D / 4; ++q) {
      float4 a = xi4[q]; float4 b = xj4[q];
      dot += a.x * b.x + a.y * b.y + a.z * b.z + a.w * b.w;
    }
    float d = pair_dist(dot, si, sq[j], oi, om[j]);
    mysum += d;
    mymax = fmaxf(mymax, d);
  }
  float s1 = wave_reduce_sum(mysum);
  float m1 = wave_reduce_max(mymax);
  int lane = t & 63, w = t >> 6;
  if (lane == 0) { red[w] = s1; red[4 + w] = m1; }
  __syncthreads();
  if (t == 0) {
    float s = red[0] + red[1];
    float m = fmaxf(red[4], red[5]);
    bool valid = (c >= 2) && (c < B);
    float hp = (c >= 2) ? m : 0.0f;
    hpm[i] = valid ? (hp + mg[i]) : -1e30f;
    if (s != 0.0f) atomicAdd(&acc[2], s);  // positive-pair distance sum
  }
}

// K5: full-matrix negative pass. 32x64 tiles, 128 threads, 4x4 micro-tile with
// strided assignment (rows tr+8m, cols tc+16n) -> LDS b128 reads hit 8
// bank-groups (2-way aliasing = free) with the +4 padded layout.
__global__ __launch_bounds__(128) void k5_main(
    const float* __restrict__ emb, const int* __restrict__ lab,
    const float* __restrict__ sq, const float* __restrict__ om,
    const float* __restrict__ hpm, float* acc, int B, int jspan) {
  __shared__ float Al[RT][D + PAD];
  __shared__ float Bl[CT][D + PAD];
  __shared__ float sqj[CT], omj[CT];
  __shared__ int   labj[CT];
  __shared__ float red[4];

  int t   = threadIdx.x;
  int rb  = blockIdx.x * RT;
  int jb0 = blockIdx.y * jspan;

  // stage A tile: RT*(D/4)=1024 float4 over 128 threads
  #pragma unroll
  for (int q = 0; q < RT * (D / 4) / 128; ++q) {
    int flat = t + q * 128;
    int r = flat >> 5;       // D/4 == 32 float4 per row
    int k4 = flat & 31;
    float4 v = reinterpret_cast<const float4*>(emb + (size_t)(rb + r) * D)[k4];
    *reinterpret_cast<float4*>(&Al[r][k4 * 4]) = v;
  }

  int tr = t >> 4;  // 0..7
  int tc = t & 15;  // 0..15
  float hp4[4], sq4[4], om4[4];
  int lb4[4];
  #pragma unroll
  for (int m = 0; m < 4; ++m) {
    int gi = rb + tr + 8 * m;
    hp4[m] = hpm[gi]; sq4[m] = sq[gi]; om4[m] = om[gi]; lb4[m] = lab[gi];
  }

  float lsum = 0.0f, lact = 0.0f;

  for (int jt = 0; jt < jspan / CT; ++jt) {
    int jb = jb0 + jt * CT;
    __syncthreads();  // previous tile fully consumed
    #pragma unroll
    for (int q = 0; q < CT * (D / 4) / 128; ++q) {
      int flat = t + q * 128;
      int c = flat >> 5;
      int k4 = flat & 31;
      float4 v = reinterpret_cast<const float4*>(emb + (size_t)(jb + c) * D)[k4];
      *reinterpret_cast<float4*>(&Bl[c][k4 * 4]) = v;
    }
    if (t < CT) {
      sqj[t] = sq[jb + t]; omj[t] = om[jb + t]; labj[t] = lab[jb + t];
    }
    __syncthreads();

    float accd[4][4];
    #pragma unroll
    for (int m = 0; m < 4; ++m)
      #pragma unroll
      for (int n = 0; n < 4; ++n) accd[m][n] = 0.0f;

    #pragma unroll 4
    for (int k4 = 0; k4 < D / 4; ++k4) {
      float4 av[4], bv[4];
      #pragma unroll
      for (int m = 0; m < 4; ++m)
        av[m] = *reinterpret_cast<const float4*>(&Al[tr + 8 * m][k4 * 4]);
      #pragma unroll
      for (int n = 0; n < 4; ++n)
        bv[n] = *reinterpret_cast<const float4*>(&Bl[tc + 16 * n][k4 * 4]);
      #pragma unroll
      for (int m = 0; m < 4; ++m)
        #pragma unroll
        for (int n = 0; n < 4; ++n)
          accd[m][n] += av[m].x * bv[n].x + av[m].y * bv[n].y +
                        av[m].z * bv[n].z + av[m].w * bv[n].w;
    }

    #pragma unroll
    for (int m = 0; m < 4; ++m) {
      #pragma unroll
      for (int n = 0; n < 4; ++n) {
        int cc = tc + 16 * n;
        if (labj[cc] != lb4[m]) {   // negative pair (includes j==i exclusion)
          float d = pair_dist(accd[m][n], sq4[m], sqj[cc], om4[m], omj[cc]);
          float raw = hp4[m] - d;   // hp4 = hardest_pos + margin (or -1e30 if invalid)
          lsum += fmaxf(raw, 0.0f);
          lact += (raw > 0.0f) ? 1.0f : 0.0f;
        }
      }
    }
  }

  float s1 = wave_reduce_sum(lsum);
  float s2 = wave_reduce_sum(lact);
  int lane = t & 63, w = t >> 6;
  if (lane == 0) { red[w] = s1; red[2 + w] = s2; }
  __syncthreads();
  if (t == 0) {
    atomicAdd(&acc[0], red[0] + red[1]);
    atomicAdd(&acc[1], red[2] + red[3]);
  }
}

// K6: finalize the 5 scalar outputs
__global__ void k6_final(const float* acc, float* out) {
  if (threadIdx.x == 0 && blockIdx.x == 0) {
    float trip  = acc[4];
    float den   = fmaxf(trip, 1.0f);
    out[0] = acc[0] / den;                                    // loss
    out[1] = acc[1];                                          // num_active
    out[2] = trip;                                            // total_triplets
    out[3] = acc[1] / den;                                    // active_ratio
    out[4] = (acc[3] > 0.0f) ? acc[2] / fmaxf(acc[3], 1.0f)   // mean_distance
                             : 0.0f;
  }
}

extern "C" void kernel_launch(void* const* d_in, const int* in_sizes, int n_in,
                              void* d_out, int out_size, void* d_ws, size_t ws_size,
                              hipStream_t stream) {
  const float* emb = (const float*)d_in[0];
  const int*   lab = (const int*)d_in[1];
  int B = in_sizes[1];

  // ws layout (floats): acc[8] | sq[B] | om[B] | mg[B] | hpm[B] | ints: LC[64] LOFF[64] LCUR[64] SIDX[B]
  float* ws   = (float*)d_ws;
  float* acc  = ws;
  float* sq   = ws + 8;
  float* om   = sq + B;
  float* mg   = om + B;
  float* hpm  = mg + B;
  int*   LC   = (int*)(hpm + B);
  int*   LOFF = LC + NL;
  int*   LCUR = LOFF + NL;
  int*   SIDX = LCUR + NL;

  k0_zero<<<1, 256, 0, stream>>>(acc, LC);
  k1_rowstats<<<(B + 3) / 4, 256, 0, stream>>>(emb, lab, sq, om, mg, LC, B);
  k2_prefix<<<1, 64, 0, stream>>>(acc, LC, LOFF, LCUR, B);
  k3_scatter<<<(B + 255) / 256, 256, 0, stream>>>(lab, LCUR, SIDX, B);
  k4_pos<<<B, 128, 0, stream>>>(emb, lab, LC, LOFF, SIDX, sq, om, mg, hpm, acc, B);

  const int jsplit = 8;
  int jspan = B / jsplit;            // 512 cols per block, 8 tiles of 64
  dim3 g5(B / RT, jsplit);
  k5_main<<<g5, 128, 0, stream>>>(emb, lab, sq, om, hpm, acc, B, jspan);

  k6_final<<<1, 64, 0, stream>>>(acc, (float*)d_out);
}

// Round 3
// 226.452 us; speedup vs baseline: 1.4866x; 1.4866x over previous
//
#include <hip/hip_runtime.h>
#include <hip/hip_bf16.h>
#include <math.h>

static constexpr int D   = 128;   // embedding dim
static constexpr int NL  = 64;    // labels in [0,64)
static constexpr int BT  = 128;   // block tile (rows == cols)

typedef __attribute__((ext_vector_type(8))) short  bf16x8;
typedef __attribute__((ext_vector_type(4))) float  f32x4;

__device__ __forceinline__ float wave_reduce_sum(float v) {
  #pragma unroll
  for (int o = 32; o; o >>= 1) v += __shfl_xor(v, o, 64);
  return v;
}
__device__ __forceinline__ float wave_reduce_max(float v) {
  #pragma unroll
  for (int o = 32; o; o >>= 1) v = fmaxf(v, __shfl_xor(v, o, 64));
  return v;
}

__device__ __forceinline__ float fast_acosh(float x) {  // x >= 1
  float s = __builtin_amdgcn_sqrtf(fmaf(x, x, -1.0f));
  return __logf(x + s);
}

// f32 -> bf16 with round-to-nearest-even (bit-level, header-independent)
__device__ __forceinline__ unsigned short f2b(float x) {
  unsigned int u = __float_as_uint(x);
  unsigned int lsb = (u >> 16) & 1u;
  u += 0x7fffu + lsb;
  return (unsigned short)(u >> 16);
}

// ---------------------------------------------------------------------------
// kA: one block. Label histogram -> prefix (LOFF[NL+1]) -> scatter SIDX,
// analytic pos_count / total_triplets, zero the accumulators.
__global__ void kA_setup(const int* __restrict__ lab, float* acc,
                         int* LOFF, int* SIDX, int B) {
  __shared__ int h[NL];
  __shared__ int cur[NL];
  int t = threadIdx.x;
  if (t < NL) h[t] = 0;
  __syncthreads();
  for (int i = t; i < B; i += 256) atomicAdd(&h[lab[i]], 1);
  __syncthreads();
  if (t == 0) {
    int off = 0;
    long long pc = 0, trip = 0;
    for (int l = 0; l < NL; ++l) {
      int c = h[l];
      LOFF[l] = off; cur[l] = off; off += c;
      pc += (long long)c * (c - 1);
      if (c >= 2 && c < B) trip += (long long)c * (B - c);
    }
    LOFF[NL] = B;
    acc[0] = 0.0f; acc[1] = 0.0f; acc[2] = 0.0f;
    acc[3] = (float)pc;    // positive pair count (< 2^24, exact)
    acc[4] = (float)trip;  // total triplets     (< 2^24, exact)
  }
  __syncthreads();
  for (int i = t; i < B; i += 256) {
    int p = atomicAdd(&cur[lab[i]], 1);
    SIDX[p] = i;
  }
}

// ---------------------------------------------------------------------------
// kB: per-row ||x||^2 and v = sqrt(2)/(1-||x||^2). One wave per row.
__global__ __launch_bounds__(256) void kB_rowstats(
    const float* __restrict__ emb, float* __restrict__ sq,
    float* __restrict__ vv, int B) {
  int w = threadIdx.x >> 6, lane = threadIdx.x & 63;
  int i = blockIdx.x * 4 + w;
  if (i >= B) return;
  float2 v = reinterpret_cast<const float2*>(emb + (size_t)i * D)[lane];
  float s = wave_reduce_sum(v.x * v.x + v.y * v.y);
  if (lane == 0) {
    sq[i] = s;
    vv[i] = 1.41421356237f / fmaxf(1.0f - s, 1e-6f);
  }
}

// ---------------------------------------------------------------------------
// kC: positive pass. One wave per anchor: hardest_pos, margin -> hpm,
// positive distance sum -> acc[2]. Same-label pairs only (~64/row).
__global__ __launch_bounds__(256) void kC_pos(
    const float* __restrict__ emb, const int* __restrict__ lab,
    const int* __restrict__ LOFF, const int* __restrict__ SIDX,
    const float* __restrict__ sq, const float* __restrict__ vv,
    float* __restrict__ hpm, float* acc, int B) {
  __shared__ float xi[4][D];
  int w = threadIdx.x >> 6, lane = threadIdx.x & 63;
  int i = blockIdx.x * 4 + w;
  float2 v2 = reinterpret_cast<const float2*>(emb + (size_t)i * D)[lane];
  xi[w][2 * lane]     = v2.x;
  xi[w][2 * lane + 1] = v2.y;
  __syncthreads();
  int li = lab[i];
  int base = LOFF[li];
  int c = LOFF[li + 1] - base;
  float si = sq[i], vi = vv[i];
  float mymax = -1e30f, mysum = 0.0f;
  const float4* xx = reinterpret_cast<const float4*>(xi[w]);
  for (int p = lane; p < c; p += 64) {
    int j = SIDX[base + p];
    if (j != i) {
      const float4* xj = reinterpret_cast<const float4*>(emb + (size_t)j * D);
      float d0 = 0, d1 = 0, d2 = 0, d3 = 0;
      #pragma unroll
      for (int q = 0; q < D / 16; ++q) {
        float4 a0 = xx[4*q+0], b0 = xj[4*q+0];
        float4 a1 = xx[4*q+1], b1 = xj[4*q+1];
        float4 a2 = xx[4*q+2], b2 = xj[4*q+2];
        float4 a3 = xx[4*q+3], b3 = xj[4*q+3];
        d0 += a0.x*b0.x + a0.y*b0.y + a0.z*b0.z + a0.w*b0.w;
        d1 += a1.x*b1.x + a1.y*b1.y + a1.z*b1.z + a1.w*b1.w;
        d2 += a2.x*b2.x + a2.y*b2.y + a2.z*b2.z + a2.w*b2.w;
        d3 += a3.x*b3.x + a3.y*b3.y + a3.z*b3.z + a3.w*b3.w;
      }
      float dot = (d0 + d1) + (d2 + d3);
      float diff = fmaxf(si + sq[j] - 2.0f * dot, 0.0f);
      float arg = fmaf(diff * vi, vv[j], 1.0f);
      float d = fast_acosh(arg);
      mysum += d;
      mymax = fmaxf(mymax, d);
    }
  }
  float s1 = wave_reduce_sum(mysum);
  float m1 = wave_reduce_max(mymax);
  if (lane == 0) {
    bool valid = (c >= 2) && (c < B);
    float mg = fmaxf(fmaf(2.0f, __builtin_amdgcn_sqrtf(si), 1.0f), 0.1f);
    hpm[i] = valid ? (m1 + mg) : -1e30f;
    if (s1 != 0.0f) atomicAdd(&acc[2], s1);
  }
}

// ---------------------------------------------------------------------------
// kD: negative pass over upper-triangular 128x128 block pairs.
// MFMA bf16 Gram tile; acosh once per unordered pair; both anchor orders
// applied on off-diagonal blocks. 256 threads = 4 waves (2x2), each wave
// owns a 64x64 quadrant as 4x4 fragments of 16x16x32.
__global__ __launch_bounds__(256) void kD_neg(
    const float* __restrict__ emb, const int* __restrict__ lab,
    const float* __restrict__ sq, const float* __restrict__ vv,
    const float* __restrict__ hpm, float* acc, int B) {
  __shared__ unsigned short Al[BT][D + 8];   // +8 bf16 pad: 2-way banks on b128
  __shared__ unsigned short Bl[BT][D + 8];
  __shared__ float rs[BT], rv[BT], rh[BT];
  __shared__ float cs[BT], cv[BT], ch[BT];
  __shared__ int   rl[BT], cl[BT];

  const int T = B / BT;
  // decode linear block id -> upper-triangular (bi, bj)
  int rem = blockIdx.x, bi = 0, rowlen = T;
  while (rem >= rowlen) { rem -= rowlen; --rowlen; ++bi; }
  int bj = bi + rem;
  const bool diag = (bi == bj);

  int t = threadIdx.x;

  { // stage f32 -> bf16 tiles (rows of A from bi, rows of B from bj)
    int r = t >> 1, hh = t & 1;
    const float* ar = emb + (size_t)(bi * BT + r) * D + hh * 64;
    const float* br = emb + (size_t)(bj * BT + r) * D + hh * 64;
    #pragma unroll
    for (int q = 0; q < 16; ++q) {
      float4 va = *reinterpret_cast<const float4*>(ar + q * 4);
      float4 vb = *reinterpret_cast<const float4*>(br + q * 4);
      ushort4 ua = { f2b(va.x), f2b(va.y), f2b(va.z), f2b(va.w) };
      ushort4 ub = { f2b(vb.x), f2b(vb.y), f2b(vb.z), f2b(vb.w) };
      *reinterpret_cast<ushort4*>(&Al[r][hh * 64 + q * 4]) = ua;
      *reinterpret_cast<ushort4*>(&Bl[r][hh * 64 + q * 4]) = ub;
    }
  }
  if (t < BT) {
    int g = bi * BT + t;
    rs[t] = sq[g]; rv[t] = vv[g]; rh[t] = hpm[g]; rl[t] = lab[g];
  } else {
    int r = t - BT, g = bj * BT + r;
    cs[r] = sq[g]; cv[r] = vv[g]; ch[r] = hpm[g]; cl[r] = lab[g];
  }
  __syncthreads();

  int wid = t >> 6, lane = t & 63;
  int wr = wid >> 1, wc = wid & 1;
  int lr = lane & 15, lg = lane >> 4;

  f32x4 dacc[4][4];
  #pragma unroll
  for (int m = 0; m < 4; ++m)
    #pragma unroll
    for (int n = 0; n < 4; ++n) dacc[m][n] = (f32x4){0.f, 0.f, 0.f, 0.f};

  #pragma unroll
  for (int kk = 0; kk < 4; ++kk) {
    bf16x8 a[4], b[4];
    #pragma unroll
    for (int m = 0; m < 4; ++m)
      a[m] = *reinterpret_cast<const bf16x8*>(&Al[wr * 64 + m * 16 + lr][kk * 32 + lg * 8]);
    #pragma unroll
    for (int n = 0; n < 4; ++n)
      b[n] = *reinterpret_cast<const bf16x8*>(&Bl[wc * 64 + n * 16 + lr][kk * 32 + lg * 8]);
    #pragma unroll
    for (int m = 0; m < 4; ++m)
      #pragma unroll
      for (int n = 0; n < 4; ++n)
        dacc[m][n] = __builtin_amdgcn_mfma_f32_16x16x32_bf16(a[m], b[n], dacc[m][n], 0, 0, 0);
  }

  const float dsec = diag ? 0.0f : 1.0f;
  float lsum = 0.0f, lact = 0.0f;
  #pragma unroll
  for (int m = 0; m < 4; ++m) {
    int r0 = wr * 64 + m * 16 + lg * 4;
    f32x4 sr = *reinterpret_cast<const f32x4*>(&rs[r0]);
    f32x4 vr = *reinterpret_cast<const f32x4*>(&rv[r0]);
    f32x4 hr = *reinterpret_cast<const f32x4*>(&rh[r0]);
    int4  lm = *reinterpret_cast<const int4*>(&rl[r0]);
    int lmv[4] = { lm.x, lm.y, lm.z, lm.w };
    #pragma unroll
    for (int n = 0; n < 4; ++n) {
      int cc = wc * 64 + n * 16 + lr;
      float sc = cs[cc], vcv = cv[cc], hc = ch[cc];
      int   lc = cl[cc];
      #pragma unroll
      for (int g = 0; g < 4; ++g) {
        float dot  = dacc[m][n][g];
        float diff = fmaxf(fmaf(-2.0f, dot, sr[g] + sc), 0.0f);
        float arg  = fmaf(diff * vr[g], vcv, 1.0f);
        float d    = fast_acosh(arg);
        float r1   = hr[g] - d;       // (row anchor) hp+margin - d, -1e30 if invalid
        float r2   = hc    - d;       // (col anchor)
        float neg  = (lmv[g] != lc) ? 1.0f : 0.0f;
        lsum += neg * (fmaxf(r1, 0.0f) + dsec * fmaxf(r2, 0.0f));
        lact += neg * ((r1 > 0.0f ? 1.0f : 0.0f) + dsec * (r2 > 0.0f ? 1.0f : 0.0f));
      }
    }
  }

  lsum = wave_reduce_sum(lsum);
  lact = wave_reduce_sum(lact);
  if (lane == 0) {
    atomicAdd(&acc[0], lsum);
    atomicAdd(&acc[1], lact);
  }
}

// ---------------------------------------------------------------------------
// kE: finalize the 5 scalar outputs
__global__ void kE_final(const float* acc, float* out) {
  if (threadIdx.x == 0 && blockIdx.x == 0) {
    float trip = acc[4];
    float den  = fmaxf(trip, 1.0f);
    out[0] = acc[0] / den;                                   // loss
    out[1] = acc[1];                                         // num_active
    out[2] = trip;                                           // total_triplets
    out[3] = acc[1] / den;                                   // active_ratio
    out[4] = (acc[3] > 0.0f) ? acc[2] / fmaxf(acc[3], 1.0f)  // mean_distance
                             : 0.0f;
  }
}

extern "C" void kernel_launch(void* const* d_in, const int* in_sizes, int n_in,
                              void* d_out, int out_size, void* d_ws, size_t ws_size,
                              hipStream_t stream) {
  const float* emb = (const float*)d_in[0];
  const int*   lab = (const int*)d_in[1];
  int B = in_sizes[1];

  // ws (floats): acc[8] | sq[B] | vv[B] | hpm[B] | ints: LOFF[NL+1] | SIDX[B]
  float* ws   = (float*)d_ws;
  float* acc  = ws;
  float* sq   = ws + 8;
  float* vv   = sq + B;
  float* hpm  = vv + B;
  int*   LOFF = (int*)(hpm + B);
  int*   SIDX = LOFF + (NL + 1);

  kA_setup<<<1, 256, 0, stream>>>(lab, acc, LOFF, SIDX, B);
  kB_rowstats<<<(B + 3) / 4, 256, 0, stream>>>(emb, sq, vv, B);
  kC_pos<<<(B + 3) / 4, 256, 0, stream>>>(emb, lab, LOFF, SIDX, sq, vv, hpm, acc, B);

  int T = B / BT;
  int nblk = T * (T + 1) / 2;
  kD_neg<<<nblk, 256, 0, stream>>>(emb, lab, sq, vv, hpm, acc, B);

  kE_final<<<1, 64, 0, stream>>>(acc, (float*)d_out);
}

// Round 4
// 109.383 us; speedup vs baseline: 3.0777x; 2.0703x over previous
//
#include <hip/hip_runtime.h>
#include <hip/hip_bf16.h>
#include <math.h>

static constexpr int D   = 128;   // embedding dim
static constexpr int NL  = 64;    // labels in [0,64)
static constexpr int BT  = 128;   // block tile (rows == cols)

typedef __attribute__((ext_vector_type(8))) short  bf16x8;
typedef __attribute__((ext_vector_type(4))) float  f32x4;

__device__ __forceinline__ float wave_reduce_sum(float v) {
  #pragma unroll
  for (int o = 32; o; o >>= 1) v += __shfl_xor(v, o, 64);
  return v;
}
__device__ __forceinline__ float wave_reduce_max(float v) {
  #pragma unroll
  for (int o = 32; o; o >>= 1) v = fmaxf(v, __shfl_xor(v, o, 64));
  return v;
}

__device__ __forceinline__ float fast_acosh(float x) {  // x >= 1
  float s = __builtin_amdgcn_sqrtf(fmaf(x, x, -1.0f));
  return __logf(x + s);
}

// f32 -> bf16 round-to-nearest-even (bit-level)
__device__ __forceinline__ unsigned short f2b(float x) {
  unsigned int u = __float_as_uint(x);
  unsigned int lsb = (u >> 16) & 1u;
  u += 0x7fffu + lsb;
  return (unsigned short)(u >> 16);
}

// ---------------------------------------------------------------------------
// kA: one block. Label histogram -> prefix (LOFF[NL+1]) -> scatter SIDX,
// analytic pos_count / total_triplets, zero the accumulators.
__global__ void kA_setup(const int* __restrict__ lab, float* acc,
                         int* LOFF, int* SIDX, int B) {
  __shared__ int h[NL];
  __shared__ int cur[NL];
  int t = threadIdx.x;
  if (t < NL) h[t] = 0;
  __syncthreads();
  for (int i = t; i < B; i += 256) atomicAdd(&h[lab[i]], 1);
  __syncthreads();
  if (t == 0) {
    int off = 0;
    long long pc = 0, trip = 0;
    for (int l = 0; l < NL; ++l) {
      int c = h[l];
      LOFF[l] = off; cur[l] = off; off += c;
      pc += (long long)c * (c - 1);
      if (c >= 2 && c < B) trip += (long long)c * (B - c);
    }
    LOFF[NL] = B;
    acc[0] = 0.0f; acc[1] = 0.0f; acc[2] = 0.0f;
    acc[3] = (float)pc;    // positive pair count (< 2^24, exact)
    acc[4] = (float)trip;  // total triplets     (< 2^24, exact)
  }
  __syncthreads();
  for (int i = t; i < B; i += 256) {
    int p = atomicAdd(&cur[lab[i]], 1);
    SIDX[p] = i;
  }
}

// ---------------------------------------------------------------------------
// kB: per-row ||x||^2 and v = sqrt(2)/(1-||x||^2). One wave per row.
__global__ __launch_bounds__(256) void kB_rowstats(
    const float* __restrict__ emb, float* __restrict__ sq,
    float* __restrict__ vv, int B) {
  int w = threadIdx.x >> 6, lane = threadIdx.x & 63;
  int i = blockIdx.x * 4 + w;
  if (i >= B) return;
  float2 v = reinterpret_cast<const float2*>(emb + (size_t)i * D)[lane];
  float s = wave_reduce_sum(v.x * v.x + v.y * v.y);
  if (lane == 0) {
    sq[i] = s;
    vv[i] = 1.41421356237f / fmaxf(1.0f - s, 1e-6f);
  }
}

// ---------------------------------------------------------------------------
// kC: positive pass, label-grouped MFMA tiles. One block per label.
// Stages the label's rows (via SIDX) as bf16 tiles, computes the c x c
// same-label distance tile, extracts per-row max (hardest_pos) and the
// ordered positive distance sum. Diagonal excluded exactly.
__global__ __launch_bounds__(256) void kC_pos(
    const float* __restrict__ emb,
    const int* __restrict__ LOFF, const int* __restrict__ SIDX,
    const float* __restrict__ sq, const float* __restrict__ vv,
    float* __restrict__ hpm, float* acc, int B) {
  __shared__ unsigned short Al[BT][D + 8];
  __shared__ unsigned short Bl[BT][D + 8];
  __shared__ float rs[BT], rv[BT];
  __shared__ float cs[BT], cv[BT];
  __shared__ float rmaxs[2][BT];
  __shared__ int   ridx[BT], cidx[BT];

  int l = blockIdx.x;
  int base = LOFF[l];
  int c = LOFF[l + 1] - base;
  if (c == 0) return;
  int t = threadIdx.x;
  int wid = t >> 6, lane = t & 63;
  int wr = wid >> 1, wc = wid & 1;
  int lr = lane & 15, lg = lane >> 4;
  const bool validc = (c >= 2) && (c < B);

  float lsum = 0.0f;

  for (int i0 = 0; i0 < c; i0 += BT) {
    int ci = min(BT, c - i0);
    __syncthreads();  // previous i-tile fully consumed
    { // stage A rows: 2 threads per row
      int r = t >> 1, hh = t & 1;
      int rr = min(r, ci - 1);
      int gi = SIDX[base + i0 + rr];
      const float* ar = emb + (size_t)gi * D + hh * 64;
      #pragma unroll
      for (int q = 0; q < 16; ++q) {
        float4 va = *reinterpret_cast<const float4*>(ar + q * 4);
        ushort4 ua = { f2b(va.x), f2b(va.y), f2b(va.z), f2b(va.w) };
        *reinterpret_cast<ushort4*>(&Al[r][hh * 64 + q * 4]) = ua;
      }
      if (hh == 0) { rs[r] = sq[gi]; rv[r] = vv[gi]; ridx[r] = gi; }
    }

    float rmax_reg[4][4];
    #pragma unroll
    for (int m = 0; m < 4; ++m)
      #pragma unroll
      for (int g = 0; g < 4; ++g) rmax_reg[m][g] = 0.0f;  // d >= 0 always

    for (int j0 = 0; j0 < c; j0 += BT) {
      int cj = min(BT, c - j0);
      __syncthreads();  // previous Bl consumed (also orders Al staging)
      { // stage B rows
        int r = t >> 1, hh = t & 1;
        int rr = min(r, cj - 1);
        int gj = SIDX[base + j0 + rr];
        const float* br = emb + (size_t)gj * D + hh * 64;
        #pragma unroll
        for (int q = 0; q < 16; ++q) {
          float4 vb = *reinterpret_cast<const float4*>(br + q * 4);
          ushort4 ub = { f2b(vb.x), f2b(vb.y), f2b(vb.z), f2b(vb.w) };
          *reinterpret_cast<ushort4*>(&Bl[r][hh * 64 + q * 4]) = ub;
        }
        if (hh == 0) { cs[r] = sq[gj]; cv[r] = vv[gj]; cidx[r] = gj; }
      }
      __syncthreads();

      f32x4 dacc[4][4];
      #pragma unroll
      for (int m = 0; m < 4; ++m)
        #pragma unroll
        for (int n = 0; n < 4; ++n) dacc[m][n] = (f32x4){0.f, 0.f, 0.f, 0.f};

      #pragma unroll
      for (int kk = 0; kk < 4; ++kk) {
        bf16x8 a[4], b[4];
        #pragma unroll
        for (int m = 0; m < 4; ++m)
          a[m] = *reinterpret_cast<const bf16x8*>(&Al[wr * 64 + m * 16 + lr][kk * 32 + lg * 8]);
        #pragma unroll
        for (int n = 0; n < 4; ++n)
          b[n] = *reinterpret_cast<const bf16x8*>(&Bl[wc * 64 + n * 16 + lr][kk * 32 + lg * 8]);
        #pragma unroll
        for (int m = 0; m < 4; ++m)
          #pragma unroll
          for (int n = 0; n < 4; ++n)
            dacc[m][n] = __builtin_amdgcn_mfma_f32_16x16x32_bf16(a[m], b[n], dacc[m][n], 0, 0, 0);
      }

      #pragma unroll
      for (int m = 0; m < 4; ++m) {
        int r0 = wr * 64 + m * 16 + lg * 4;
        #pragma unroll
        for (int n = 0; n < 4; ++n) {
          int cc = wc * 64 + n * 16 + lr;
          if (cc < cj) {
            float sc = cs[cc], vcv = cv[cc];
            int   gj = cidx[cc];
            #pragma unroll
            for (int g = 0; g < 4; ++g) {
              int rloc = r0 + g;
              if (rloc < ci && ridx[rloc] != gj) {
                float diff = fmaxf(fmaf(-2.0f, dacc[m][n][g], rs[rloc] + sc), 0.0f);
                float arg  = fmaf(diff * rv[rloc], vcv, 1.0f);
                float d    = fast_acosh(arg);
                lsum += d;
                rmax_reg[m][g] = fmaxf(rmax_reg[m][g], d);
              }
            }
          }
        }
      }
    }

    // per-row max: reduce across the 16 lr lanes, combine 2 wc waves via LDS
    #pragma unroll
    for (int m = 0; m < 4; ++m)
      #pragma unroll
      for (int g = 0; g < 4; ++g) {
        float v = rmax_reg[m][g];
        v = fmaxf(v, __shfl_xor(v, 1, 64));
        v = fmaxf(v, __shfl_xor(v, 2, 64));
        v = fmaxf(v, __shfl_xor(v, 4, 64));
        v = fmaxf(v, __shfl_xor(v, 8, 64));
        if (lr == 0) rmaxs[wc][wr * 64 + m * 16 + lg * 4 + g] = v;
      }
    __syncthreads();
    if (t < BT && t < ci) {
      float mx = fmaxf(rmaxs[0][t], rmaxs[1][t]);
      int gi = ridx[t];
      float mg = fmaxf(fmaf(2.0f, __builtin_amdgcn_sqrtf(rs[t]), 1.0f), 0.1f);
      hpm[gi] = validc ? (mx + mg) : -1e30f;
    }
  }

  lsum = wave_reduce_sum(lsum);
  if (lane == 0 && lsum != 0.0f) atomicAdd(&acc[2], lsum);
}

// ---------------------------------------------------------------------------
// kD: negative pass over upper-triangular 128x128 block pairs.
// MFMA bf16 Gram tile; acosh once per unordered pair; both anchor orders
// applied on off-diagonal blocks.
__global__ __launch_bounds__(256) void kD_neg(
    const float* __restrict__ emb, const int* __restrict__ lab,
    const float* __restrict__ sq, const float* __restrict__ vv,
    const float* __restrict__ hpm, float* acc, int B) {
  __shared__ unsigned short Al[BT][D + 8];
  __shared__ unsigned short Bl[BT][D + 8];
  __shared__ float rs[BT], rv[BT], rh[BT];
  __shared__ float cs[BT], cv[BT], ch[BT];
  __shared__ int   rl[BT], cl[BT];

  const int T = B / BT;
  int rem = blockIdx.x, bi = 0, rowlen = T;
  while (rem >= rowlen) { rem -= rowlen; --rowlen; ++bi; }
  int bj = bi + rem;
  const bool diag = (bi == bj);

  int t = threadIdx.x;

  {
    int r = t >> 1, hh = t & 1;
    const float* ar = emb + (size_t)(bi * BT + r) * D + hh * 64;
    const float* br = emb + (size_t)(bj * BT + r) * D + hh * 64;
    #pragma unroll
    for (int q = 0; q < 16; ++q) {
      float4 va = *reinterpret_cast<const float4*>(ar + q * 4);
      float4 vb = *reinterpret_cast<const float4*>(br + q * 4);
      ushort4 ua = { f2b(va.x), f2b(va.y), f2b(va.z), f2b(va.w) };
      ushort4 ub = { f2b(vb.x), f2b(vb.y), f2b(vb.z), f2b(vb.w) };
      *reinterpret_cast<ushort4*>(&Al[r][hh * 64 + q * 4]) = ua;
      *reinterpret_cast<ushort4*>(&Bl[r][hh * 64 + q * 4]) = ub;
    }
  }
  if (t < BT) {
    int g = bi * BT + t;
    rs[t] = sq[g]; rv[t] = vv[g]; rh[t] = hpm[g]; rl[t] = lab[g];
  } else {
    int r = t - BT, g = bj * BT + r;
    cs[r] = sq[g]; cv[r] = vv[g]; ch[r] = hpm[g]; cl[r] = lab[g];
  }
  __syncthreads();

  int wid = t >> 6, lane = t & 63;
  int wr = wid >> 1, wc = wid & 1;
  int lr = lane & 15, lg = lane >> 4;

  f32x4 dacc[4][4];
  #pragma unroll
  for (int m = 0; m < 4; ++m)
    #pragma unroll
    for (int n = 0; n < 4; ++n) dacc[m][n] = (f32x4){0.f, 0.f, 0.f, 0.f};

  #pragma unroll
  for (int kk = 0; kk < 4; ++kk) {
    bf16x8 a[4], b[4];
    #pragma unroll
    for (int m = 0; m < 4; ++m)
      a[m] = *reinterpret_cast<const bf16x8*>(&Al[wr * 64 + m * 16 + lr][kk * 32 + lg * 8]);
    #pragma unroll
    for (int n = 0; n < 4; ++n)
      b[n] = *reinterpret_cast<const bf16x8*>(&Bl[wc * 64 + n * 16 + lr][kk * 32 + lg * 8]);
    #pragma unroll
    for (int m = 0; m < 4; ++m)
      #pragma unroll
      for (int n = 0; n < 4; ++n)
        dacc[m][n] = __builtin_amdgcn_mfma_f32_16x16x32_bf16(a[m], b[n], dacc[m][n], 0, 0, 0);
  }

  const float dsec = diag ? 0.0f : 1.0f;
  float lsum = 0.0f, lact = 0.0f;
  #pragma unroll
  for (int m = 0; m < 4; ++m) {
    int r0 = wr * 64 + m * 16 + lg * 4;
    f32x4 sr = *reinterpret_cast<const f32x4*>(&rs[r0]);
    f32x4 vr = *reinterpret_cast<const f32x4*>(&rv[r0]);
    f32x4 hr = *reinterpret_cast<const f32x4*>(&rh[r0]);
    int4  lm = *reinterpret_cast<const int4*>(&rl[r0]);
    int lmv[4] = { lm.x, lm.y, lm.z, lm.w };
    #pragma unroll
    for (int n = 0; n < 4; ++n) {
      int cc = wc * 64 + n * 16 + lr;
      float sc = cs[cc], vcv = cv[cc], hc = ch[cc];
      int   lc = cl[cc];
      #pragma unroll
      for (int g = 0; g < 4; ++g) {
        float dot  = dacc[m][n][g];
        float diff = fmaxf(fmaf(-2.0f, dot, sr[g] + sc), 0.0f);
        float arg  = fmaf(diff * vr[g], vcv, 1.0f);
        float d    = fast_acosh(arg);
        float r1   = hr[g] - d;
        float r2   = hc    - d;
        float neg  = (lmv[g] != lc) ? 1.0f : 0.0f;
        lsum += neg * (fmaxf(r1, 0.0f) + dsec * fmaxf(r2, 0.0f));
        lact += neg * ((r1 > 0.0f ? 1.0f : 0.0f) + dsec * (r2 > 0.0f ? 1.0f : 0.0f));
      }
    }
  }

  lsum = wave_reduce_sum(lsum);
  lact = wave_reduce_sum(lact);
  if (lane == 0) {
    atomicAdd(&acc[0], lsum);
    atomicAdd(&acc[1], lact);
  }
}

// ---------------------------------------------------------------------------
// kE: finalize the 5 scalar outputs
__global__ void kE_final(const float* acc, float* out) {
  if (threadIdx.x == 0 && blockIdx.x == 0) {
    float trip = acc[4];
    float den  = fmaxf(trip, 1.0f);
    out[0] = acc[0] / den;
    out[1] = acc[1];
    out[2] = trip;
    out[3] = acc[1] / den;
    out[4] = (acc[3] > 0.0f) ? acc[2] / fmaxf(acc[3], 1.0f) : 0.0f;
  }
}

extern "C" void kernel_launch(void* const* d_in, const int* in_sizes, int n_in,
                              void* d_out, int out_size, void* d_ws, size_t ws_size,
                              hipStream_t stream) {
  const float* emb = (const float*)d_in[0];
  const int*   lab = (const int*)d_in[1];
  int B = in_sizes[1];

  // ws (floats): acc[8] | sq[B] | vv[B] | hpm[B] | ints: LOFF[NL+1] | SIDX[B]
  float* ws   = (float*)d_ws;
  float* acc  = ws;
  float* sq   = ws + 8;
  float* vv   = sq + B;
  float* hpm  = vv + B;
  int*   LOFF = (int*)(hpm + B);
  int*   SIDX = LOFF + (NL + 1);

  kA_setup<<<1, 256, 0, stream>>>(lab, acc, LOFF, SIDX, B);
  kB_rowstats<<<(B + 3) / 4, 256, 0, stream>>>(emb, sq, vv, B);
  kC_pos<<<NL, 256, 0, stream>>>(emb, LOFF, SIDX, sq, vv, hpm, acc, B);

  int T = B / BT;
  int nblk = T * (T + 1) / 2;
  kD_neg<<<nblk, 256, 0, stream>>>(emb, lab, sq, vv, hpm, acc, B);

  kE_final<<<1, 64, 0, stream>>>(acc, (float*)d_out);
}

// Round 5
// 57.722 us; speedup vs baseline: 5.8322x; 1.8950x over previous
//
#include <hip/hip_runtime.h>
#include <hip/hip_bf16.h>
#include <math.h>

static constexpr int D   = 128;   // embedding dim
static constexpr int NL  = 64;    // labels in [0,64)
static constexpr int BT  = 128;   // kC tile
static constexpr int NT  = 64;    // kD tile (64x64 triangular)

typedef __attribute__((ext_vector_type(8))) short  bf16x8;
typedef __attribute__((ext_vector_type(4))) float  f32x4;

__device__ __forceinline__ float wave_reduce_sum(float v) {
  #pragma unroll
  for (int o = 32; o; o >>= 1) v += __shfl_xor(v, o, 64);
  return v;
}

__device__ __forceinline__ float fast_acosh(float x) {  // x >= 1
  float s = __builtin_amdgcn_sqrtf(fmaf(x, x, -1.0f));
  return __logf(x + s);
}

// f32 -> bf16 round-to-nearest-even (bit-level)
__device__ __forceinline__ unsigned short f2b(float x) {
  unsigned int u = __float_as_uint(x);
  unsigned int lsb = (u >> 16) & 1u;
  u += 0x7fffu + lsb;
  return (unsigned short)(u >> 16);
}

// ---------------------------------------------------------------------------
// kA: one block. Label histogram -> prefix (LOFF[NL+1]) -> scatter SIDX,
// analytic pos_count / total_triplets, zero the accumulators.
__global__ void kA_setup(const int* __restrict__ lab, float* acc,
                         int* LOFF, int* SIDX, int B) {
  __shared__ int h[NL];
  __shared__ int cur[NL];
  int t = threadIdx.x;
  if (t < NL) h[t] = 0;
  __syncthreads();
  for (int i = t; i < B; i += 256) atomicAdd(&h[lab[i]], 1);
  __syncthreads();
  if (t == 0) {
    int off = 0;
    long long pc = 0, trip = 0;
    for (int l = 0; l < NL; ++l) {
      int c = h[l];
      LOFF[l] = off; cur[l] = off; off += c;
      pc += (long long)c * (c - 1);
      if (c >= 2 && c < B) trip += (long long)c * (B - c);
    }
    LOFF[NL] = B;
    acc[0] = 0.0f; acc[1] = 0.0f; acc[2] = 0.0f;
    acc[3] = (float)pc;    // positive pair count (< 2^24, exact)
    acc[4] = (float)trip;  // total triplets     (< 2^24, exact)
  }
  __syncthreads();
  for (int i = t; i < B; i += 256) {
    int p = atomicAdd(&cur[lab[i]], 1);
    SIDX[p] = i;
  }
}

// ---------------------------------------------------------------------------
// kB: per-row ||x||^2 and v = sqrt(2)/(1-||x||^2). One wave per row.
__global__ __launch_bounds__(256) void kB_rowstats(
    const float* __restrict__ emb, float* __restrict__ sq,
    float* __restrict__ vv, int B) {
  int w = threadIdx.x >> 6, lane = threadIdx.x & 63;
  int i = blockIdx.x * 4 + w;
  if (i >= B) return;
  float2 v = reinterpret_cast<const float2*>(emb + (size_t)i * D)[lane];
  float s = wave_reduce_sum(v.x * v.x + v.y * v.y);
  if (lane == 0) {
    sq[i] = s;
    vv[i] = 1.41421356237f / fmaxf(1.0f - s, 1e-6f);
  }
}

// ---------------------------------------------------------------------------
// kC: positive pass, label-grouped MFMA tiles. One block per label.
__global__ __launch_bounds__(256) void kC_pos(
    const float* __restrict__ emb,
    const int* __restrict__ LOFF, const int* __restrict__ SIDX,
    const float* __restrict__ sq, const float* __restrict__ vv,
    float* __restrict__ hpm, float* acc, int B) {
  __shared__ unsigned short Al[BT][D + 8];
  __shared__ unsigned short Bl[BT][D + 8];
  __shared__ float rs[BT], rv[BT];
  __shared__ float cs[BT], cv[BT];
  __shared__ float rmaxs[2][BT];
  __shared__ int   ridx[BT], cidx[BT];

  int l = blockIdx.x;
  int base = LOFF[l];
  int c = LOFF[l + 1] - base;
  if (c == 0) return;
  int t = threadIdx.x;
  int wid = t >> 6, lane = t & 63;
  int wr = wid >> 1, wc = wid & 1;
  int lr = lane & 15, lg = lane >> 4;
  const bool validc = (c >= 2) && (c < B);

  float lsum = 0.0f;

  for (int i0 = 0; i0 < c; i0 += BT) {
    int ci = min(BT, c - i0);
    __syncthreads();
    {
      int r = t >> 1, hh = t & 1;
      int rr = min(r, ci - 1);
      int gi = SIDX[base + i0 + rr];
      const float* ar = emb + (size_t)gi * D + hh * 64;
      #pragma unroll
      for (int q = 0; q < 16; ++q) {
        float4 va = *reinterpret_cast<const float4*>(ar + q * 4);
        ushort4 ua = { f2b(va.x), f2b(va.y), f2b(va.z), f2b(va.w) };
        *reinterpret_cast<ushort4*>(&Al[r][hh * 64 + q * 4]) = ua;
      }
      if (hh == 0) { rs[r] = sq[gi]; rv[r] = vv[gi]; ridx[r] = gi; }
    }

    float rmax_reg[4][4];
    #pragma unroll
    for (int m = 0; m < 4; ++m)
      #pragma unroll
      for (int g = 0; g < 4; ++g) rmax_reg[m][g] = 0.0f;

    for (int j0 = 0; j0 < c; j0 += BT) {
      int cj = min(BT, c - j0);
      __syncthreads();
      {
        int r = t >> 1, hh = t & 1;
        int rr = min(r, cj - 1);
        int gj = SIDX[base + j0 + rr];
        const float* br = emb + (size_t)gj * D + hh * 64;
        #pragma unroll
        for (int q = 0; q < 16; ++q) {
          float4 vb = *reinterpret_cast<const float4*>(br + q * 4);
          ushort4 ub = { f2b(vb.x), f2b(vb.y), f2b(vb.z), f2b(vb.w) };
          *reinterpret_cast<ushort4*>(&Bl[r][hh * 64 + q * 4]) = ub;
        }
        if (hh == 0) { cs[r] = sq[gj]; cv[r] = vv[gj]; cidx[r] = gj; }
      }
      __syncthreads();

      f32x4 dacc[4][4];
      #pragma unroll
      for (int m = 0; m < 4; ++m)
        #pragma unroll
        for (int n = 0; n < 4; ++n) dacc[m][n] = (f32x4){0.f, 0.f, 0.f, 0.f};

      #pragma unroll
      for (int kk = 0; kk < 4; ++kk) {
        bf16x8 a[4], b[4];
        #pragma unroll
        for (int m = 0; m < 4; ++m)
          a[m] = *reinterpret_cast<const bf16x8*>(&Al[wr * 64 + m * 16 + lr][kk * 32 + lg * 8]);
        #pragma unroll
        for (int n = 0; n < 4; ++n)
          b[n] = *reinterpret_cast<const bf16x8*>(&Bl[wc * 64 + n * 16 + lr][kk * 32 + lg * 8]);
        #pragma unroll
        for (int m = 0; m < 4; ++m)
          #pragma unroll
          for (int n = 0; n < 4; ++n)
            dacc[m][n] = __builtin_amdgcn_mfma_f32_16x16x32_bf16(a[m], b[n], dacc[m][n], 0, 0, 0);
      }

      #pragma unroll
      for (int m = 0; m < 4; ++m) {
        int r0 = wr * 64 + m * 16 + lg * 4;
        #pragma unroll
        for (int n = 0; n < 4; ++n) {
          int cc = wc * 64 + n * 16 + lr;
          if (cc < cj) {
            float sc = cs[cc], vcv = cv[cc];
            int   gj = cidx[cc];
            #pragma unroll
            for (int g = 0; g < 4; ++g) {
              int rloc = r0 + g;
              if (rloc < ci && ridx[rloc] != gj) {
                float diff = fmaxf(fmaf(-2.0f, dacc[m][n][g], rs[rloc] + sc), 0.0f);
                float arg  = fmaf(diff * rv[rloc], vcv, 1.0f);
                float d    = fast_acosh(arg);
                lsum += d;
                rmax_reg[m][g] = fmaxf(rmax_reg[m][g], d);
              }
            }
          }
        }
      }
    }

    #pragma unroll
    for (int m = 0; m < 4; ++m)
      #pragma unroll
      for (int g = 0; g < 4; ++g) {
        float v = rmax_reg[m][g];
        v = fmaxf(v, __shfl_xor(v, 1, 64));
        v = fmaxf(v, __shfl_xor(v, 2, 64));
        v = fmaxf(v, __shfl_xor(v, 4, 64));
        v = fmaxf(v, __shfl_xor(v, 8, 64));
        if (lr == 0) rmaxs[wc][wr * 64 + m * 16 + lg * 4 + g] = v;
      }
    __syncthreads();
    if (t < BT && t < ci) {
      float mx = fmaxf(rmaxs[0][t], rmaxs[1][t]);
      int gi = ridx[t];
      float mg = fmaxf(fmaf(2.0f, __builtin_amdgcn_sqrtf(rs[t]), 1.0f), 0.1f);
      hpm[gi] = validc ? (mx + mg) : -1e30f;
    }
  }

  lsum = wave_reduce_sum(lsum);
  if (lane == 0 && lsum != 0.0f) atomicAdd(&acc[2], lsum);
}

// ---------------------------------------------------------------------------
// kD: negative pass, 64x64 triangular tiles, coalesced staging, no atomics.
// Each block writes its (loss_sum, active_cnt) partials to part[2*bid(+1)].
__global__ __launch_bounds__(256) void kD_neg(
    const float* __restrict__ emb, const int* __restrict__ lab,
    const float* __restrict__ sq, const float* __restrict__ vv,
    const float* __restrict__ hpm, float* __restrict__ part, int B) {
  __shared__ unsigned short Al[NT][D + 8];
  __shared__ unsigned short Bl[NT][D + 8];
  __shared__ float rs[NT], rv[NT], rh[NT];
  __shared__ float cs[NT], cv[NT], ch[NT];
  __shared__ int   rl[NT], cl[NT];
  __shared__ float red[8];

  const int T = B / NT;                 // 64
  int bid = blockIdx.x;
  // closed-form triangular decode: bi s.t. off(bi) <= bid < off(bi+1),
  // off(x) = x*T - x*(x-1)/2
  float disc = (float)((2 * T + 1) * (2 * T + 1) - 8 * bid);
  int bi = (int)(((float)(2 * T + 1) - __builtin_amdgcn_sqrtf(disc)) * 0.5f);
  bi = max(0, min(bi, T - 1));
  while (bi * T - bi * (bi - 1) / 2 > bid) --bi;
  while ((bi + 1) * T - (bi + 1) * bi / 2 <= bid) ++bi;
  int bj = bi + (bid - (bi * T - bi * (bi - 1) / 2));
  const bool diag = (bi == bj);

  int t = threadIdx.x;

  // coalesced staging: lane-consecutive float4 (1KB per wave-instr)
  const float* abase = emb + (size_t)bi * NT * D;
  const float* bbase = emb + (size_t)bj * NT * D;
  #pragma unroll
  for (int p = 0; p < NT * (D / 4) / 256; ++p) {    // 8 iterations
    int idx = t + p * 256;
    int r = idx >> 5, c4 = idx & 31;
    float4 va = reinterpret_cast<const float4*>(abase)[idx];
    float4 vb = reinterpret_cast<const float4*>(bbase)[idx];
    ushort4 ua = { f2b(va.x), f2b(va.y), f2b(va.z), f2b(va.w) };
    ushort4 ub = { f2b(vb.x), f2b(vb.y), f2b(vb.z), f2b(vb.w) };
    *reinterpret_cast<ushort4*>(&Al[r][c4 * 4]) = ua;
    *reinterpret_cast<ushort4*>(&Bl[r][c4 * 4]) = ub;
  }
  if (t < NT) {
    int g = bi * NT + t;
    rs[t] = sq[g]; rv[t] = vv[g]; rh[t] = hpm[g]; rl[t] = lab[g];
  } else if (t < 2 * NT) {
    int r = t - NT, g = bj * NT + r;
    cs[r] = sq[g]; cv[r] = vv[g]; ch[r] = hpm[g]; cl[r] = lab[g];
  }
  __syncthreads();

  int wid = t >> 6, lane = t & 63;
  int lr = lane & 15, lg = lane >> 4;

  // wave `wid` owns rows wid*16..+15, all 64 cols
  f32x4 dacc[4];
  #pragma unroll
  for (int n = 0; n < 4; ++n) dacc[n] = (f32x4){0.f, 0.f, 0.f, 0.f};

  #pragma unroll
  for (int kk = 0; kk < 4; ++kk) {
    bf16x8 a = *reinterpret_cast<const bf16x8*>(&Al[wid * 16 + lr][kk * 32 + lg * 8]);
    bf16x8 b[4];
    #pragma unroll
    for (int n = 0; n < 4; ++n)
      b[n] = *reinterpret_cast<const bf16x8*>(&Bl[n * 16 + lr][kk * 32 + lg * 8]);
    #pragma unroll
    for (int n = 0; n < 4; ++n)
      dacc[n] = __builtin_amdgcn_mfma_f32_16x16x32_bf16(a, b[n], dacc[n], 0, 0, 0);
  }

  const float dsec = diag ? 0.0f : 1.0f;
  float lsum = 0.0f, lact = 0.0f;
  int r0 = wid * 16 + lg * 4;
  f32x4 sr = *reinterpret_cast<const f32x4*>(&rs[r0]);
  f32x4 vr = *reinterpret_cast<const f32x4*>(&rv[r0]);
  f32x4 hr = *reinterpret_cast<const f32x4*>(&rh[r0]);
  int4  lm = *reinterpret_cast<const int4*>(&rl[r0]);
  int lmv[4] = { lm.x, lm.y, lm.z, lm.w };
  #pragma unroll
  for (int n = 0; n < 4; ++n) {
    int cc = n * 16 + lr;
    float sc = cs[cc], vcv = cv[cc], hc = ch[cc];
    int   lc = cl[cc];
    #pragma unroll
    for (int g = 0; g < 4; ++g) {
      float dot  = dacc[n][g];
      float diff = fmaxf(fmaf(-2.0f, dot, sr[g] + sc), 0.0f);
      float arg  = fmaf(diff * vr[g], vcv, 1.0f);
      float d    = fast_acosh(arg);
      float r1   = hr[g] - d;
      float r2   = hc    - d;
      float neg  = (lmv[g] != lc) ? 1.0f : 0.0f;
      lsum += neg * (fmaxf(r1, 0.0f) + dsec * fmaxf(r2, 0.0f));
      lact += neg * ((r1 > 0.0f ? 1.0f : 0.0f) + dsec * (r2 > 0.0f ? 1.0f : 0.0f));
    }
  }

  lsum = wave_reduce_sum(lsum);
  lact = wave_reduce_sum(lact);
  if (lane == 0) { red[wid] = lsum; red[4 + wid] = lact; }
  __syncthreads();
  if (t == 0) {
    part[2 * bid]     = (red[0] + red[1]) + (red[2] + red[3]);
    part[2 * bid + 1] = (red[4] + red[5]) + (red[6] + red[7]);
  }
}

// ---------------------------------------------------------------------------
// kE: tree-reduce per-block partials + finalize the 5 outputs
__global__ __launch_bounds__(256) void kE_final(
    const float* __restrict__ part, int nblk, const float* acc, float* out) {
  __shared__ float sl[256], sa[256];
  int t = threadIdx.x;
  float s = 0.0f, a = 0.0f;
  for (int i = t; i < nblk; i += 256) {
    s += part[2 * i];
    a += part[2 * i + 1];
  }
  sl[t] = s; sa[t] = a;
  __syncthreads();
  for (int o = 128; o; o >>= 1) {
    if (t < o) { sl[t] += sl[t + o]; sa[t] += sa[t + o]; }
    __syncthreads();
  }
  if (t == 0) {
    float trip = acc[4];
    float den  = fmaxf(trip, 1.0f);
    out[0] = sl[0] / den;                                   // loss
    out[1] = sa[0];                                         // num_active
    out[2] = trip;                                          // total_triplets
    out[3] = sa[0] / den;                                   // active_ratio
    out[4] = (acc[3] > 0.0f) ? acc[2] / fmaxf(acc[3], 1.0f) // mean_distance
                             : 0.0f;
  }
}

extern "C" void kernel_launch(void* const* d_in, const int* in_sizes, int n_in,
                              void* d_out, int out_size, void* d_ws, size_t ws_size,
                              hipStream_t stream) {
  const float* emb = (const float*)d_in[0];
  const int*   lab = (const int*)d_in[1];
  int B = in_sizes[1];

  int T = B / NT;
  int nblk = T * (T + 1) / 2;

  // ws (floats): acc[8] | sq[B] | vv[B] | hpm[B] | LOFF[NL+1] | SIDX[B] | part[2*nblk]
  float* ws   = (float*)d_ws;
  float* acc  = ws;
  float* sq   = ws + 8;
  float* vv   = sq + B;
  float* hpm  = vv + B;
  int*   LOFF = (int*)(hpm + B);
  int*   SIDX = LOFF + (NL + 1);
  float* part = (float*)(SIDX + B);

  kA_setup<<<1, 256, 0, stream>>>(lab, acc, LOFF, SIDX, B);
  kB_rowstats<<<(B + 3) / 4, 256, 0, stream>>>(emb, sq, vv, B);
  kC_pos<<<NL, 256, 0, stream>>>(emb, LOFF, SIDX, sq, vv, hpm, acc, B);
  kD_neg<<<nblk, 256, 0, stream>>>(emb, lab, sq, vv, hpm, part, B);
  kE_final<<<1, 256, 0, stream>>>(part, nblk, acc, (float*)d_out);
}

// Round 6
// 54.825 us; speedup vs baseline: 6.1404x; 1.0528x over previous
//
#include <hip/hip_runtime.h>
#include <hip/hip_bf16.h>
#include <math.h>

static constexpr int D   = 128;   // embedding dim
static constexpr int NL  = 64;    // labels in [0,64)
static constexpr int NT  = 64;    // tile size (kC and kD)

typedef __attribute__((ext_vector_type(8))) short  bf16x8;
typedef __attribute__((ext_vector_type(4))) float  f32x4;

__device__ __forceinline__ float wave_reduce_sum(float v) {
  #pragma unroll
  for (int o = 32; o; o >>= 1) v += __shfl_xor(v, o, 64);
  return v;
}

__device__ __forceinline__ float fast_acosh(float x) {  // x >= 1
  float s = __builtin_amdgcn_sqrtf(fmaf(x, x, -1.0f));
  return __logf(x + s);
}

// f32 -> bf16 round-to-nearest-even (bit-level)
__device__ __forceinline__ unsigned short f2b(float x) {
  unsigned int u = __float_as_uint(x);
  unsigned int lsb = (u >> 16) & 1u;
  u += 0x7fffu + lsb;
  return (unsigned short)(u >> 16);
}

// ---------------------------------------------------------------------------
// kAB: fused setup + rowstats.
//  blocks 0..B/4-1 : per-row ||x||^2 and v = sqrt(2)/(1-||x||^2), 4 rows/block
//  block  B/4      : label histogram -> prefix LOFF[NL+1] -> scatter SIDX,
//                    analytic pos_count / total_triplets, zero accumulators.
__global__ __launch_bounds__(256) void kAB_setup(
    const float* __restrict__ emb, const int* __restrict__ lab,
    float* acc, int* LOFF, int* SIDX,
    float* __restrict__ sq, float* __restrict__ vv, int B) {
  int t = threadIdx.x;
  if ((int)blockIdx.x < B / 4) {
    int w = t >> 6, lane = t & 63;
    int i = blockIdx.x * 4 + w;
    float2 v = reinterpret_cast<const float2*>(emb + (size_t)i * D)[lane];
    float s = wave_reduce_sum(v.x * v.x + v.y * v.y);
    if (lane == 0) {
      sq[i] = s;
      vv[i] = 1.41421356237f / fmaxf(1.0f - s, 1e-6f);
    }
    return;
  }
  // setup block
  __shared__ int h[NL];
  __shared__ int cur[NL];
  if (t < NL) h[t] = 0;
  __syncthreads();
  for (int i = t; i < B; i += 256) atomicAdd(&h[lab[i]], 1);
  __syncthreads();
  if (t == 0) {
    int off = 0;
    long long pc = 0, trip = 0;
    for (int l = 0; l < NL; ++l) {
      int c = h[l];
      LOFF[l] = off; cur[l] = off; off += c;
      pc += (long long)c * (c - 1);
      if (c >= 2 && c < B) trip += (long long)c * (B - c);
    }
    LOFF[NL] = B;
    acc[0] = 0.0f; acc[1] = 0.0f; acc[2] = 0.0f;
    acc[3] = (float)pc;    // positive pair count (< 2^24, exact)
    acc[4] = (float)trip;  // total triplets     (< 2^24, exact)
  }
  __syncthreads();
  for (int i = t; i < B; i += 256) {
    int p = atomicAdd(&cur[lab[i]], 1);
    SIDX[p] = i;
  }
}

// ---------------------------------------------------------------------------
// kC: positive pass, one block per label, 64x64 tiles, coalesced SIDX gather.
// Wave wid owns rows wid*16..+15 of the tile; per-row max stays in-wave.
__global__ __launch_bounds__(256) void kC_pos(
    const float* __restrict__ emb,
    const int* __restrict__ LOFF, const int* __restrict__ SIDX,
    const float* __restrict__ sq, const float* __restrict__ vv,
    float* __restrict__ hpm, float* acc, int B) {
  __shared__ unsigned short Al[NT][D + 8];
  __shared__ unsigned short Bl[NT][D + 8];
  __shared__ float rs[NT], rv[NT];
  __shared__ float cs[NT], cv[NT];
  __shared__ int   ridx[NT], cidx[NT];

  int l = blockIdx.x;
  int base = LOFF[l];
  int c = LOFF[l + 1] - base;
  if (c == 0) return;
  int t = threadIdx.x;
  int wid = t >> 6, lane = t & 63;
  int lr = lane & 15, lg = lane >> 4;
  const bool validc = (c >= 2) && (c < B);

  float lsum = 0.0f;

  for (int i0 = 0; i0 < c; i0 += NT) {
    int ci = min(NT, c - i0);
    __syncthreads();  // previous i-tile's Al/rs fully consumed
    #pragma unroll
    for (int p = 0; p < 8; ++p) {     // 64 rows x 32 float4, lane-consecutive
      int idx = t + p * 256;
      int r = idx >> 5, c4 = idx & 31;
      int gi = SIDX[base + i0 + min(r, ci - 1)];
      float4 va = reinterpret_cast<const float4*>(emb + (size_t)gi * D)[c4];
      ushort4 ua = { f2b(va.x), f2b(va.y), f2b(va.z), f2b(va.w) };
      *reinterpret_cast<ushort4*>(&Al[r][c4 * 4]) = ua;
    }
    if (t < NT) {
      int gi = SIDX[base + i0 + min(t, ci - 1)];
      rs[t] = sq[gi]; rv[t] = vv[gi]; ridx[t] = gi;
    }

    float rmax[4] = {0.0f, 0.0f, 0.0f, 0.0f};   // d >= 0 always

    for (int j0 = 0; j0 < c; j0 += NT) {
      int cj = min(NT, c - j0);
      __syncthreads();  // previous Bl consumed (also orders Al staging)
      #pragma unroll
      for (int p = 0; p < 8; ++p) {
        int idx = t + p * 256;
        int r = idx >> 5, c4 = idx & 31;
        int gj = SIDX[base + j0 + min(r, cj - 1)];
        float4 vb = reinterpret_cast<const float4*>(emb + (size_t)gj * D)[c4];
        ushort4 ub = { f2b(vb.x), f2b(vb.y), f2b(vb.z), f2b(vb.w) };
        *reinterpret_cast<ushort4*>(&Bl[r][c4 * 4]) = ub;
      }
      if (t < NT) {
        int gj = SIDX[base + j0 + min(t, cj - 1)];
        cs[t] = sq[gj]; cv[t] = vv[gj]; cidx[t] = gj;
      }
      __syncthreads();

      f32x4 dacc[4];
      #pragma unroll
      for (int n = 0; n < 4; ++n) dacc[n] = (f32x4){0.f, 0.f, 0.f, 0.f};
      #pragma unroll
      for (int kk = 0; kk < 4; ++kk) {
        bf16x8 a = *reinterpret_cast<const bf16x8*>(&Al[wid * 16 + lr][kk * 32 + lg * 8]);
        bf16x8 b[4];
        #pragma unroll
        for (int n = 0; n < 4; ++n)
          b[n] = *reinterpret_cast<const bf16x8*>(&Bl[n * 16 + lr][kk * 32 + lg * 8]);
        #pragma unroll
        for (int n = 0; n < 4; ++n)
          dacc[n] = __builtin_amdgcn_mfma_f32_16x16x32_bf16(a, b[n], dacc[n], 0, 0, 0);
      }

      int r0 = wid * 16 + lg * 4;
      #pragma unroll
      for (int n = 0; n < 4; ++n) {
        int cc = n * 16 + lr;
        float sc = cs[cc], vcv = cv[cc];
        int   gj = cidx[cc];
        #pragma unroll
        for (int g = 0; g < 4; ++g) {
          int rloc = r0 + g;
          if (rloc < ci && cc < cj && ridx[rloc] != gj) {
            float diff = fmaxf(fmaf(-2.0f, dacc[n][g], rs[rloc] + sc), 0.0f);
            float arg  = fmaf(diff * rv[rloc], vcv, 1.0f);
            float d    = fast_acosh(arg);
            lsum += d;
            rmax[g] = fmaxf(rmax[g], d);
          }
        }
      }
    }

    // per-row max: reduce across the 16 lr lanes (rows live in one wave)
    int r0 = wid * 16 + lg * 4;
    #pragma unroll
    for (int g = 0; g < 4; ++g) {
      float v = rmax[g];
      v = fmaxf(v, __shfl_xor(v, 1, 64));
      v = fmaxf(v, __shfl_xor(v, 2, 64));
      v = fmaxf(v, __shfl_xor(v, 4, 64));
      v = fmaxf(v, __shfl_xor(v, 8, 64));
      int rloc = r0 + g;
      if (lr == 0 && rloc < ci) {
        float mg = fmaxf(fmaf(2.0f, __builtin_amdgcn_sqrtf(rs[rloc]), 1.0f), 0.1f);
        hpm[ridx[rloc]] = validc ? (v + mg) : -1e30f;
      }
    }
  }

  lsum = wave_reduce_sum(lsum);
  if (lane == 0 && lsum != 0.0f) atomicAdd(&acc[2], lsum);
}

// ---------------------------------------------------------------------------
// kD: negative pass, 64x64 triangular tiles, coalesced staging, no atomics.
__global__ __launch_bounds__(256) void kD_neg(
    const float* __restrict__ emb, const int* __restrict__ lab,
    const float* __restrict__ sq, const float* __restrict__ vv,
    const float* __restrict__ hpm, float* __restrict__ part, int B) {
  __shared__ unsigned short Al[NT][D + 8];
  __shared__ unsigned short Bl[NT][D + 8];
  __shared__ float rs[NT], rv[NT], rh[NT];
  __shared__ float cs[NT], cv[NT], ch[NT];
  __shared__ int   rl[NT], cl[NT];
  __shared__ float red[8];

  const int T = B / NT;
  int bid = blockIdx.x;
  float disc = (float)((2 * T + 1) * (2 * T + 1) - 8 * bid);
  int bi = (int)(((float)(2 * T + 1) - __builtin_amdgcn_sqrtf(disc)) * 0.5f);
  bi = max(0, min(bi, T - 1));
  while (bi * T - bi * (bi - 1) / 2 > bid) --bi;
  while ((bi + 1) * T - (bi + 1) * bi / 2 <= bid) ++bi;
  int bj = bi + (bid - (bi * T - bi * (bi - 1) / 2));
  const bool diag = (bi == bj);

  int t = threadIdx.x;

  const float* abase = emb + (size_t)bi * NT * D;
  const float* bbase = emb + (size_t)bj * NT * D;
  #pragma unroll
  for (int p = 0; p < NT * (D / 4) / 256; ++p) {
    int idx = t + p * 256;
    int r = idx >> 5, c4 = idx & 31;
    float4 va = reinterpret_cast<const float4*>(abase)[idx];
    float4 vb = reinterpret_cast<const float4*>(bbase)[idx];
    ushort4 ua = { f2b(va.x), f2b(va.y), f2b(va.z), f2b(va.w) };
    ushort4 ub = { f2b(vb.x), f2b(vb.y), f2b(vb.z), f2b(vb.w) };
    *reinterpret_cast<ushort4*>(&Al[r][c4 * 4]) = ua;
    *reinterpret_cast<ushort4*>(&Bl[r][c4 * 4]) = ub;
  }
  if (t < NT) {
    int g = bi * NT + t;
    rs[t] = sq[g]; rv[t] = vv[g]; rh[t] = hpm[g]; rl[t] = lab[g];
  } else if (t < 2 * NT) {
    int r = t - NT, g = bj * NT + r;
    cs[r] = sq[g]; cv[r] = vv[g]; ch[r] = hpm[g]; cl[r] = lab[g];
  }
  __syncthreads();

  int wid = t >> 6, lane = t & 63;
  int lr = lane & 15, lg = lane >> 4;

  f32x4 dacc[4];
  #pragma unroll
  for (int n = 0; n < 4; ++n) dacc[n] = (f32x4){0.f, 0.f, 0.f, 0.f};

  #pragma unroll
  for (int kk = 0; kk < 4; ++kk) {
    bf16x8 a = *reinterpret_cast<const bf16x8*>(&Al[wid * 16 + lr][kk * 32 + lg * 8]);
    bf16x8 b[4];
    #pragma unroll
    for (int n = 0; n < 4; ++n)
      b[n] = *reinterpret_cast<const bf16x8*>(&Bl[n * 16 + lr][kk * 32 + lg * 8]);
    #pragma unroll
    for (int n = 0; n < 4; ++n)
      dacc[n] = __builtin_amdgcn_mfma_f32_16x16x32_bf16(a, b[n], dacc[n], 0, 0, 0);
  }

  const float dsec = diag ? 0.0f : 1.0f;
  float lsum = 0.0f, lact = 0.0f;
  int r0 = wid * 16 + lg * 4;
  f32x4 sr = *reinterpret_cast<const f32x4*>(&rs[r0]);
  f32x4 vr = *reinterpret_cast<const f32x4*>(&rv[r0]);
  f32x4 hr = *reinterpret_cast<const f32x4*>(&rh[r0]);
  int4  lm = *reinterpret_cast<const int4*>(&rl[r0]);
  int lmv[4] = { lm.x, lm.y, lm.z, lm.w };
  #pragma unroll
  for (int n = 0; n < 4; ++n) {
    int cc = n * 16 + lr;
    float sc = cs[cc], vcv = cv[cc], hc = ch[cc];
    int   lc = cl[cc];
    #pragma unroll
    for (int g = 0; g < 4; ++g) {
      float dot  = dacc[n][g];
      float diff = fmaxf(fmaf(-2.0f, dot, sr[g] + sc), 0.0f);
      float arg  = fmaf(diff * vr[g], vcv, 1.0f);
      float d    = fast_acosh(arg);
      float r1   = hr[g] - d;
      float r2   = hc    - d;
      float neg  = (lmv[g] != lc) ? 1.0f : 0.0f;
      lsum += neg * (fmaxf(r1, 0.0f) + dsec * fmaxf(r2, 0.0f));
      lact += neg * ((r1 > 0.0f ? 1.0f : 0.0f) + dsec * (r2 > 0.0f ? 1.0f : 0.0f));
    }
  }

  lsum = wave_reduce_sum(lsum);
  lact = wave_reduce_sum(lact);
  if (lane == 0) { red[wid] = lsum; red[4 + wid] = lact; }
  __syncthreads();
  if (t == 0) {
    part[2 * bid]     = (red[0] + red[1]) + (red[2] + red[3]);
    part[2 * bid + 1] = (red[4] + red[5]) + (red[6] + red[7]);
  }
}

// ---------------------------------------------------------------------------
// kE: tree-reduce per-block partials + finalize the 5 outputs
__global__ __launch_bounds__(256) void kE_final(
    const float* __restrict__ part, int nblk, const float* acc, float* out) {
  __shared__ float sl[256], sa[256];
  int t = threadIdx.x;
  float s = 0.0f, a = 0.0f;
  for (int i = t; i < nblk; i += 256) {
    s += part[2 * i];
    a += part[2 * i + 1];
  }
  sl[t] = s; sa[t] = a;
  __syncthreads();
  for (int o = 128; o; o >>= 1) {
    if (t < o) { sl[t] += sl[t + o]; sa[t] += sa[t + o]; }
    __syncthreads();
  }
  if (t == 0) {
    float trip = acc[4];
    float den  = fmaxf(trip, 1.0f);
    out[0] = sl[0] / den;                                   // loss
    out[1] = sa[0];                                         // num_active
    out[2] = trip;                                          // total_triplets
    out[3] = sa[0] / den;                                   // active_ratio
    out[4] = (acc[3] > 0.0f) ? acc[2] / fmaxf(acc[3], 1.0f) // mean_distance
                             : 0.0f;
  }
}

extern "C" void kernel_launch(void* const* d_in, const int* in_sizes, int n_in,
                              void* d_out, int out_size, void* d_ws, size_t ws_size,
                              hipStream_t stream) {
  const float* emb = (const float*)d_in[0];
  const int*   lab = (const int*)d_in[1];
  int B = in_sizes[1];

  int T = B / NT;
  int nblk = T * (T + 1) / 2;

  // ws (floats): acc[8] | sq[B] | vv[B] | hpm[B] | LOFF[NL+1] | SIDX[B] | part[2*nblk]
  float* ws   = (float*)d_ws;
  float* acc  = ws;
  float* sq   = ws + 8;
  float* vv   = sq + B;
  float* hpm  = vv + B;
  int*   LOFF = (int*)(hpm + B);
  int*   SIDX = LOFF + (NL + 1);
  float* part = (float*)(SIDX + B);

  kAB_setup<<<B / 4 + 1, 256, 0, stream>>>(emb, lab, acc, LOFF, SIDX, sq, vv, B);
  kC_pos<<<NL, 256, 0, stream>>>(emb, LOFF, SIDX, sq, vv, hpm, acc, B);
  kD_neg<<<nblk, 256, 0, stream>>>(emb, lab, sq, vv, hpm, part, B);
  kE_final<<<1, 256, 0, stream>>>(part, nblk, acc, (float*)d_out);
}